// Round 2
// baseline (1530.838 us; speedup 1.0000x reference)
//
#include <hip/hip_runtime.h>
#include <hip/hip_bf16.h>

// GraphAttentionLayer: B=16, N=2048, F_IN=256, H=128
// All float tensors fp32 (reference dtype); adj int32; output fp32.

#define BDIM 16
#define NDIM 2048
#define FIN 256
#define HDIM 128
#define NEG_BIG -3.0e38f

// ---------------- Kernel 1: wh[row][h] = X[row,:] . W[h,:] + bW[h]
// block: 256 threads = 128 h x 2 row-parities; 16 rows per block.
__global__ __launch_bounds__(256) void k_wh(const float* __restrict__ X,
                                            const float* __restrict__ W,
                                            const float* __restrict__ bW,
                                            float* __restrict__ wh) {
    __shared__ float xs[16][FIN];  // 16 KB
    const int tid = threadIdx.x;
    const long row0 = (long)blockIdx.x * 16;

    // stage 16 rows of X into LDS (1024 float4 chunks)
    #pragma unroll
    for (int u = 0; u < 4; u++) {
        int idx4 = tid + u * 256;
        int r = idx4 >> 6, f0 = (idx4 & 63) * 4;
        *reinterpret_cast<float4*>(&xs[r][f0]) =
            *reinterpret_cast<const float4*>(X + (row0 + r) * FIN + f0);
    }
    __syncthreads();

    const int h = tid & 127;
    const int rpar = tid >> 7;  // 0 or 1
    float acc[8];
    #pragma unroll
    for (int r = 0; r < 8; r++) acc[r] = 0.0f;

    const float* Wp = W + h * FIN;
    for (int f8 = 0; f8 < FIN / 8; f8++) {
        const float4 w0 = *reinterpret_cast<const float4*>(Wp + f8 * 8);
        const float4 w1 = *reinterpret_cast<const float4*>(Wp + f8 * 8 + 4);
        #pragma unroll
        for (int r = 0; r < 8; r++) {
            const float4 x0 = *reinterpret_cast<const float4*>(&xs[2 * r + rpar][f8 * 8]);
            const float4 x1 = *reinterpret_cast<const float4*>(&xs[2 * r + rpar][f8 * 8 + 4]);
            acc[r] += x0.x * w0.x + x0.y * w0.y + x0.z * w0.z + x0.w * w0.w
                    + x1.x * w1.x + x1.y * w1.y + x1.z * w1.z + x1.w * w1.w;
        }
    }

    const float bwv = bW[h];
    #pragma unroll
    for (int r = 0; r < 8; r++) {
        int rl = 2 * r + rpar;
        wh[(row0 + rl) * HDIM + h] = acc[r] + bwv;
    }
}

// ---------------- Kernel 1b: src[row] = wh[row,:].a1 ; dst[row] = wh[row,:].a2
// one wave per row, 4 rows per block
__global__ __launch_bounds__(256) void k_srcdst(const float* __restrict__ wh,
                                                const float* __restrict__ a,
                                                float* __restrict__ src,
                                                float* __restrict__ dst) {
    const int row = blockIdx.x * 4 + (threadIdx.x >> 6);
    const int lane = threadIdx.x & 63;
    const float* p = wh + (long)row * HDIM;
    float v0 = p[lane], v1 = p[64 + lane];
    float a10 = a[lane], a11 = a[64 + lane];
    float a20 = a[HDIM + lane], a21 = a[HDIM + 64 + lane];
    float s1 = v0 * a10 + v1 * a11;
    float s2 = v0 * a20 + v1 * a21;
    #pragma unroll
    for (int m = 32; m > 0; m >>= 1) {
        s1 += __shfl_xor(s1, m);
        s2 += __shfl_xor(s2, m);
    }
    if (lane == 0) { src[row] = s1; dst[row] = s2; }
}

// ---------------- Kernel 2: per row masked-softmax stats (m, 1/l)
// one block (256 thr) per (b,i) row; e-values cached in registers
__global__ __launch_bounds__(256) void k_ml(const int* __restrict__ adj,
                                            const float* __restrict__ src,
                                            const float* __restrict__ dst,
                                            const float* __restrict__ ba_p,
                                            float* __restrict__ mrow,
                                            float* __restrict__ linv) {
    __shared__ float red[8];
    const int row = blockIdx.x;   // 0..B*N-1
    const int b = row >> 11;      // row / N
    const int tid = threadIdx.x;
    const float si = src[row] + ba_p[0];
    const int4* arow4 = reinterpret_cast<const int4*>(adj + (long)row * NDIM);
    const float4* d4 = reinterpret_cast<const float4*>(dst + b * NDIM);

    float e[8];
    #pragma unroll
    for (int k = 0; k < 2; k++) {
        int q = tid + k * 256;  // 0..511 int4 chunks
        int4 av = arow4[q];
        float4 dv = d4[q];
        float x0 = si + dv.x, x1 = si + dv.y, x2 = si + dv.z, x3 = si + dv.w;
        x0 = x0 > 0.f ? x0 : 0.01f * x0;
        x1 = x1 > 0.f ? x1 : 0.01f * x1;
        x2 = x2 > 0.f ? x2 : 0.01f * x2;
        x3 = x3 > 0.f ? x3 : 0.01f * x3;
        e[4 * k + 0] = av.x > 0 ? x0 : NEG_BIG;
        e[4 * k + 1] = av.y > 0 ? x1 : NEG_BIG;
        e[4 * k + 2] = av.z > 0 ? x2 : NEG_BIG;
        e[4 * k + 3] = av.w > 0 ? x3 : NEG_BIG;
    }
    float m = NEG_BIG;
    #pragma unroll
    for (int k = 0; k < 8; k++) m = fmaxf(m, e[k]);
    #pragma unroll
    for (int o = 32; o > 0; o >>= 1) m = fmaxf(m, __shfl_xor(m, o));
    if ((tid & 63) == 0) red[tid >> 6] = m;
    __syncthreads();
    m = fmaxf(fmaxf(red[0], red[1]), fmaxf(red[2], red[3]));

    float s = 0.0f;
    #pragma unroll
    for (int k = 0; k < 8; k++) s += __expf(e[k] - m);
    #pragma unroll
    for (int o = 32; o > 0; o >>= 1) s += __shfl_xor(s, o);
    if ((tid & 63) == 0) red[4 + (tid >> 6)] = s;
    __syncthreads();
    if (tid == 0) {
        float l = red[4] + red[5] + red[6] + red[7];
        mrow[row] = m;
        linv[row] = l > 0.0f ? 1.0f / l : 0.0f;
    }
}

// ---------------- Kernel 3: out[b,i,h] = elu( sum_j w(b,i,j) * wh[b,j,h] )
// block: 256 thr, TI=32 i-rows, loop j in tiles of TJ=64
#define TI 32
#define TJ 64
__global__ __launch_bounds__(256) void k_attn(const int* __restrict__ adj,
                                              const float* __restrict__ wh,
                                              const float* __restrict__ src,
                                              const float* __restrict__ dst,
                                              const float* __restrict__ mrow,
                                              const float* __restrict__ linv,
                                              const float* __restrict__ ba_p,
                                              float* __restrict__ out) {
    __shared__ float whs[TJ][HDIM];  // 32 KB
    __shared__ float wt[TI][TJ];     // 8 KB
    __shared__ float s_src[TI], s_m[TI], s_li[TI];

    const int tid = threadIdx.x;
    const int b = blockIdx.x >> 6;   // 64 i-tiles per batch
    const int it = blockIdx.x & 63;
    const int i0 = it * TI;

    if (tid < TI) {
        int row = b * NDIM + i0 + tid;
        s_src[tid] = src[row] + ba_p[0];
        s_m[tid] = mrow[row];
        s_li[tid] = linv[row];
    }
    __syncthreads();

    const int hq = tid & 31;   // h quad: h = 4*hq..4*hq+3
    const int ig = tid >> 5;   // 0..7 -> rows ig*4..ig*4+3
    float acc[4][4];
    #pragma unroll
    for (int r = 0; r < 4; r++)
        #pragma unroll
        for (int c = 0; c < 4; c++) acc[r][c] = 0.0f;

    const float* dstb = dst + b * NDIM;
    const long adjbase = ((long)b * NDIM + i0) * NDIM;
    const float* whb = wh + ((long)b * NDIM) * HDIM;

    for (int j0 = 0; j0 < NDIM; j0 += TJ) {
        // stage wh j-tile
        #pragma unroll
        for (int u = 0; u < 8; u++) {
            int idx4 = tid + u * 256;          // 0..2047 float4s
            int jj = idx4 >> 5, h4 = (idx4 & 31) * 4;
            *reinterpret_cast<float4*>(&whs[jj][h4]) =
                *reinterpret_cast<const float4*>(&whb[(long)(j0 + jj) * HDIM + h4]);
        }
        // compute weight tile
        #pragma unroll
        for (int u = 0; u < 8; u++) {
            int idx = tid + u * 256;           // 0..2047
            int i = idx >> 6, jj = idx & 63;
            int av = adj[adjbase + (long)i * NDIM + j0 + jj];
            float x = s_src[i] + dstb[j0 + jj];
            x = x > 0.f ? x : 0.01f * x;
            x = av > 0 ? x : NEG_BIG;
            wt[i][jj] = __expf(x - s_m[i]) * s_li[i];
        }
        __syncthreads();
        // accumulate
        #pragma unroll
        for (int jj = 0; jj < TJ; jj += 4) {
            float4 v0 = *reinterpret_cast<const float4*>(&whs[jj + 0][hq * 4]);
            float4 v1 = *reinterpret_cast<const float4*>(&whs[jj + 1][hq * 4]);
            float4 v2 = *reinterpret_cast<const float4*>(&whs[jj + 2][hq * 4]);
            float4 v3 = *reinterpret_cast<const float4*>(&whs[jj + 3][hq * 4]);
            #pragma unroll
            for (int r = 0; r < 4; r++) {
                float4 w = *reinterpret_cast<const float4*>(&wt[ig * 4 + r][jj]);
                acc[r][0] += w.x * v0.x + w.y * v1.x + w.z * v2.x + w.w * v3.x;
                acc[r][1] += w.x * v0.y + w.y * v1.y + w.z * v2.y + w.w * v3.y;
                acc[r][2] += w.x * v0.z + w.y * v1.z + w.z * v2.z + w.w * v3.z;
                acc[r][3] += w.x * v0.w + w.y * v1.w + w.z * v2.w + w.w * v3.w;
            }
        }
        __syncthreads();
    }

    // epilogue: ELU + store
    const long outbase = ((long)b * NDIM + i0) * HDIM;
    #pragma unroll
    for (int r = 0; r < 4; r++) {
        int i = ig * 4 + r;
        #pragma unroll
        for (int c = 0; c < 4; c++) {
            float x = acc[r][c];
            x = x > 0.f ? x : (__expf(x) - 1.0f);
            out[outbase + (long)i * HDIM + hq * 4 + c] = x;
        }
    }
}

extern "C" void kernel_launch(void* const* d_in, const int* in_sizes, int n_in,
                              void* d_out, int out_size, void* d_ws, size_t ws_size,
                              hipStream_t stream) {
    const float* X  = (const float*)d_in[0];   // [16,2048,256]
    const int* adj  = (const int*)d_in[1];     // [16,2048,2048]
    const float* W  = (const float*)d_in[2];   // [128,256]
    const float* bW = (const float*)d_in[3];   // [128]
    const float* a  = (const float*)d_in[4];   // [1,256]
    const float* ba = (const float*)d_in[5];   // [1]
    float* out = (float*)d_out;                // [16,2048,128]

    float* wh   = (float*)d_ws;                       // B*N*H fp32
    float* srcv = wh + (size_t)BDIM * NDIM * HDIM;    // B*N
    float* dstv = srcv + BDIM * NDIM;                 // B*N
    float* mrow = dstv + BDIM * NDIM;                 // B*N
    float* liv  = mrow + BDIM * NDIM;                 // B*N

    k_wh<<<BDIM * NDIM / 16, 256, 0, stream>>>(X, W, bW, wh);
    k_srcdst<<<BDIM * NDIM / 4, 256, 0, stream>>>(wh, a, srcv, dstv);
    k_ml<<<BDIM * NDIM, 256, 0, stream>>>(adj, srcv, dstv, ba, mrow, liv);
    k_attn<<<BDIM * (NDIM / TI), 256, 0, stream>>>(adj, wh, srcv, dstv, mrow, liv, ba, out);
}

// Round 3
// 497.331 us; speedup vs baseline: 3.0781x; 3.0781x over previous
//
#include <hip/hip_runtime.h>

// GraphAttentionLayer: B=16, N=2048, F_IN=256, H=128 (fp32 in/out, adj int32)
// 2-kernel fused design:
//  k_wh  : wh = X@W^T + bW (fp32), src/dst dots fused, bf16 transposed wh_T out
//  k_attn: unnormalized-softmax MFMA attention; normalization folded into epilogue
//          (softmax scale diag(1/l) factors out of att@wh; exp without max-sub is
//           safe in fp32 since |src+dst+ba| <~ 20)

#define BDIM 16
#define NDIM 2048
#define FIN 256
#define HDIM 128

typedef short short8 __attribute__((ext_vector_type(8)));
typedef float floatx4 __attribute__((ext_vector_type(4)));

__device__ __forceinline__ unsigned short f2bf(float x) {
    unsigned int u = __float_as_uint(x);
    unsigned int r = (u + 0x7fffu + ((u >> 16) & 1u)) >> 16;  // RNE
    return (unsigned short)r;
}

// ---------------- Kernel 1: wh + src/dst + bf16 transpose ----------------
// 16 rows per block; 256 thr = 128 h x 2 row-parities.
__global__ __launch_bounds__(256) void k_wh(const float* __restrict__ X,
                                            const float* __restrict__ W,
                                            const float* __restrict__ bW,
                                            const float* __restrict__ a,
                                            float* __restrict__ src,
                                            float* __restrict__ dst,
                                            unsigned short* __restrict__ whbT) {
    __shared__ float xs[16][FIN];                 // 16 KB
    __shared__ float sred[2][16][2];              // [wave-half][row][src/dst]
    __shared__ unsigned short tbuf[HDIM][16];     // 4 KB transposed bf16

    const int tid = threadIdx.x;
    const long row0 = (long)blockIdx.x * 16;

    #pragma unroll
    for (int u = 0; u < 4; u++) {
        int idx4 = tid + u * 256;
        int r = idx4 >> 6, f0 = (idx4 & 63) * 4;
        *reinterpret_cast<float4*>(&xs[r][f0]) =
            *reinterpret_cast<const float4*>(X + (row0 + r) * FIN + f0);
    }
    __syncthreads();

    const int h = tid & 127;
    const int rpar = tid >> 7;
    float acc[8];
    #pragma unroll
    for (int r = 0; r < 8; r++) acc[r] = 0.0f;

    const float* Wp = W + h * FIN;
    for (int f8 = 0; f8 < FIN / 8; f8++) {
        const float4 w0 = *reinterpret_cast<const float4*>(Wp + f8 * 8);
        const float4 w1 = *reinterpret_cast<const float4*>(Wp + f8 * 8 + 4);
        #pragma unroll
        for (int r = 0; r < 8; r++) {
            const float4 x0 = *reinterpret_cast<const float4*>(&xs[2 * r + rpar][f8 * 8]);
            const float4 x1 = *reinterpret_cast<const float4*>(&xs[2 * r + rpar][f8 * 8 + 4]);
            acc[r] += x0.x * w0.x + x0.y * w0.y + x0.z * w0.z + x0.w * w0.w
                    + x1.x * w1.x + x1.y * w1.y + x1.z * w1.z + x1.w * w1.w;
        }
    }

    const float bwv = bW[h];
    float whv[8];
    #pragma unroll
    for (int r = 0; r < 8; r++) whv[r] = acc[r] + bwv;

    // src/dst partial dot with a1/a2, reduce across the wave's 64 h-lanes
    const float a1h = a[h], a2h = a[HDIM + h];
    float s1[8], s2[8];
    #pragma unroll
    for (int r = 0; r < 8; r++) { s1[r] = whv[r] * a1h; s2[r] = whv[r] * a2h; }
    #pragma unroll
    for (int o = 32; o > 0; o >>= 1) {
        #pragma unroll
        for (int r = 0; r < 8; r++) {
            s1[r] += __shfl_xor(s1[r], o);
            s2[r] += __shfl_xor(s2[r], o);
        }
    }
    const int lane = tid & 63;
    const int half = (tid >> 6) & 1;   // h 0-63 vs 64-127
    if (lane == 0) {
        #pragma unroll
        for (int r = 0; r < 8; r++) {
            sred[half][2 * r + rpar][0] = s1[r];
            sred[half][2 * r + rpar][1] = s2[r];
        }
    }
    // bf16 transpose staging
    #pragma unroll
    for (int r = 0; r < 8; r++) tbuf[h][2 * r + rpar] = f2bf(whv[r]);
    __syncthreads();

    const int b = (int)(row0 >> 11);
    const int n0 = (int)(row0 & 2047);
    if (tid < 32) {
        int row = tid >> 1, v = tid & 1;
        float val = sred[0][row][v] + sred[1][row][v];
        if (v == 0) src[row0 + row] = val;
        else        dst[row0 + row] = val;
    }
    {
        int hh = tid >> 1, ng = (tid & 1) * 8;
        *reinterpret_cast<uint4*>(whbT + ((size_t)(b * HDIM + hh)) * NDIM + n0 + ng) =
            *reinterpret_cast<const uint4*>(&tbuf[hh][ng]);
    }
}

// ---------------- Kernel 2: fused masked-softmax attention via MFMA ----------------
// TI=64 i-rows x full H=128 per block; j-tiles of 64. 4 waves:
// wave w -> i-block (w&1)*32, h-block (w>>1)*64 (2x 16-row MFMA i-tiles, 4x 16-col h-tiles)
#define TI 64
#define TJ 64
#define LDP 72   // padded LDS row (bf16) to break power-of-2 bank stride

__global__ __launch_bounds__(256) void k_attn(const int* __restrict__ adj,
                                              const unsigned short* __restrict__ whbT,
                                              const float* __restrict__ src,
                                              const float* __restrict__ dst,
                                              const float* __restrict__ ba_p,
                                              float* __restrict__ out) {
    __shared__ unsigned short whsT[HDIM][LDP];   // 18 KB  [h][j] bf16
    __shared__ unsigned short wt[TI][LDP];       // 9 KB   [i][j] bf16 (unnormalized weights)
    __shared__ float s_src[TI];
    __shared__ float lred[TI][4];
    __shared__ float linv_s[TI];

    const int tid = threadIdx.x;
    const int b = blockIdx.x >> 5;            // 32 i-tiles per batch
    const int i0 = (blockIdx.x & 31) * TI;

    if (tid < TI) s_src[tid] = src[b * NDIM + i0 + tid] + ba_p[0];
    __syncthreads();

    const int wave = tid >> 6, lane = tid & 63;
    const int wtrow = tid >> 2, wtg = tid & 3;
    const long adjrow = ((long)(b * NDIM + i0 + wtrow)) * NDIM;
    const float* dstb = dst + b * NDIM;
    const unsigned short* whb = whbT + (size_t)b * HDIM * NDIM;

    floatx4 acc[2][4];
    #pragma unroll
    for (int mi = 0; mi < 2; mi++)
        #pragma unroll
        for (int hj = 0; hj < 4; hj++)
            acc[mi][hj] = (floatx4){0.f, 0.f, 0.f, 0.f};
    float lpart = 0.f;

    const int ib = (wave & 1) * 32;
    const int hb = (wave >> 1) * 64;
    const int lm = lane & 15, q = lane >> 4;

    for (int j0 = 0; j0 < NDIM; j0 += TJ) {
        // stage whsT tile: [128h][64j] bf16, rows contiguous in global
        #pragma unroll
        for (int u = 0; u < 4; u++) {
            int idx = tid + u * 256;
            int hh = idx >> 3, c = idx & 7;
            *reinterpret_cast<uint4*>(&whsT[hh][c * 8]) =
                *reinterpret_cast<const uint4*>(whb + (size_t)hh * NDIM + j0 + c * 8);
        }
        // unnormalized weight tile: w~ = adj ? exp(leaky(src_i+dst_j+ba)) : 0
        const float si = s_src[wtrow];
        #pragma unroll
        for (int qq = 0; qq < 4; qq++) {
            int jj = qq * 16 + wtg * 4;
            int4 av = *reinterpret_cast<const int4*>(adj + adjrow + j0 + jj);
            float4 dv = *reinterpret_cast<const float4*>(dstb + j0 + jj);
            float x0 = si + dv.x, x1 = si + dv.y, x2 = si + dv.z, x3 = si + dv.w;
            x0 = x0 > 0.f ? x0 : 0.01f * x0;
            x1 = x1 > 0.f ? x1 : 0.01f * x1;
            x2 = x2 > 0.f ? x2 : 0.01f * x2;
            x3 = x3 > 0.f ? x3 : 0.01f * x3;
            float w0 = av.x > 0 ? __expf(x0) : 0.f;
            float w1 = av.y > 0 ? __expf(x1) : 0.f;
            float w2 = av.z > 0 ? __expf(x2) : 0.f;
            float w3 = av.w > 0 ? __expf(x3) : 0.f;
            lpart += (w0 + w1) + (w2 + w3);
            union { unsigned short u[4]; uint2 v; } p;
            p.u[0] = f2bf(w0); p.u[1] = f2bf(w1); p.u[2] = f2bf(w2); p.u[3] = f2bf(w3);
            *reinterpret_cast<uint2*>(&wt[wtrow][jj]) = p.v;
        }
        __syncthreads();
        // MFMA: A=wt[i][j] (k-contig), B=wh[j][h] read from whsT[h][j] (k-contig)
        #pragma unroll
        for (int k0 = 0; k0 < TJ; k0 += 32) {
            short8 af[2], bfr[4];
            af[0] = *reinterpret_cast<const short8*>(&wt[ib + lm][k0 + q * 8]);
            af[1] = *reinterpret_cast<const short8*>(&wt[ib + 16 + lm][k0 + q * 8]);
            #pragma unroll
            for (int hj = 0; hj < 4; hj++)
                bfr[hj] = *reinterpret_cast<const short8*>(&whsT[hb + hj * 16 + lm][k0 + q * 8]);
            #pragma unroll
            for (int mi = 0; mi < 2; mi++)
                #pragma unroll
                for (int hj = 0; hj < 4; hj++)
                    acc[mi][hj] = __builtin_amdgcn_mfma_f32_16x16x32_bf16(
                        af[mi], bfr[hj], acc[mi][hj], 0, 0, 0);
        }
        __syncthreads();
    }

    // row-sum reduction -> 1/l
    lred[wtrow][wtg] = lpart;
    __syncthreads();
    if (tid < TI) {
        float l = lred[tid][0] + lred[tid][1] + lred[tid][2] + lred[tid][3];
        linv_s[tid] = l > 0.f ? 1.f / l : 0.f;
    }
    __syncthreads();

    // epilogue: scale by 1/l, ELU, store (C/D: col=lane&15, row=quad*4+reg)
    #pragma unroll
    for (int mi = 0; mi < 2; mi++) {
        #pragma unroll
        for (int r = 0; r < 4; r++) {
            int il = ib + mi * 16 + q * 4 + r;
            float li = linv_s[il];
            long obase = ((long)(b * NDIM + i0 + il)) * HDIM + hb + lm;
            #pragma unroll
            for (int hj = 0; hj < 4; hj++) {
                float x = acc[mi][hj][r] * li;
                x = x > 0.f ? x : (__expf(x) - 1.f);
                out[obase + hj * 16] = x;
            }
        }
    }
}

extern "C" void kernel_launch(void* const* d_in, const int* in_sizes, int n_in,
                              void* d_out, int out_size, void* d_ws, size_t ws_size,
                              hipStream_t stream) {
    const float* X  = (const float*)d_in[0];   // [16,2048,256]
    const int* adj  = (const int*)d_in[1];     // [16,2048,2048]
    const float* W  = (const float*)d_in[2];   // [128,256]
    const float* bW = (const float*)d_in[3];   // [128]
    const float* a  = (const float*)d_in[4];   // [1,256]
    const float* ba = (const float*)d_in[5];   // [1]
    float* out = (float*)d_out;                // [16,2048,128]

    float* srcv = (float*)d_ws;                        // B*N
    float* dstv = srcv + BDIM * NDIM;                  // B*N
    unsigned short* whbT = (unsigned short*)(dstv + BDIM * NDIM);  // B*H*N bf16 (8 MB)

    k_wh<<<BDIM * NDIM / 16, 256, 0, stream>>>(X, W, bW, a, srcv, dstv, whbT);
    k_attn<<<BDIM * (NDIM / TI), 256, 0, stream>>>(adj, whbT, srcv, dstv, ba, out);
}

// Round 4
// 438.396 us; speedup vs baseline: 3.4919x; 1.1344x over previous
//
#include <hip/hip_runtime.h>

// GraphAttentionLayer: B=16, N=2048, F_IN=256, H=128 (fp32 in/out, adj int32)
//  k_wh  : MFMA bf16x3-split GEMM wh = X@W^T + bW; fused src/dst dots + bf16
//          transposed wh_T out (no fp32-input MFMA on CDNA4 -> hi/lo split)
//  k_attn: unnormalized-softmax MFMA attention; normalization in epilogue

#define BDIM 16
#define NDIM 2048
#define FIN 256
#define HDIM 128

typedef short short8 __attribute__((ext_vector_type(8)));
typedef float floatx4 __attribute__((ext_vector_type(4)));

__device__ __forceinline__ unsigned short f2bf(float x) {
    unsigned int u = __float_as_uint(x);
    unsigned int r = (u + 0x7fffu + ((u >> 16) & 1u)) >> 16;  // RNE
    return (unsigned short)r;
}
__device__ __forceinline__ float bf2f(unsigned short s) {
    return __uint_as_float(((unsigned int)s) << 16);
}

// ---------------- Kernel 1: wh via MFMA (bf16 hi/lo split) ----------------
// 64 rows x 128 h per block; 4 waves = 4 m-tiles of 16; K staged in panels of 64.
__global__ __launch_bounds__(256) void k_wh(const float* __restrict__ X,
                                            const float* __restrict__ W,
                                            const float* __restrict__ bW,
                                            const float* __restrict__ a,
                                            float* __restrict__ src,
                                            float* __restrict__ dst,
                                            unsigned short* __restrict__ whbT) {
    __shared__ short lds[27648];                    // 54 KB
    short (*ah)[72] = (short(*)[72])lds;            // A hi  [64][72]
    short (*al)[72] = (short(*)[72])(lds + 4608);   // A lo  [64][72]
    short (*bh)[72] = (short(*)[72])(lds + 9216);   // B hi  [128][72]
    short (*bl)[72] = (short(*)[72])(lds + 18432);  // B lo  [128][72]
    short (*tb)[72] = (short(*)[72])lds;            // epilogue transpose [128][72] (alias)

    const int tid = threadIdx.x;
    const long row0 = (long)blockIdx.x * 64;
    const int w = tid >> 6, lane = tid & 63;
    const int lm = lane & 15, q = lane >> 4;

    // per-lane epilogue constants: h = nt*16 + lm
    float a1v[8], a2v[8], bwv[8];
    #pragma unroll
    for (int nt = 0; nt < 8; nt++) {
        a1v[nt] = a[nt * 16 + lm];
        a2v[nt] = a[HDIM + nt * 16 + lm];
        bwv[nt] = bW[nt * 16 + lm];
    }

    floatx4 acc[8];
    #pragma unroll
    for (int nt = 0; nt < 8; nt++) acc[nt] = (floatx4){0.f, 0.f, 0.f, 0.f};

    for (int k0 = 0; k0 < FIN; k0 += 64) {
        // stage A panel: X[row0..+64][k0..+64] -> hi/lo bf16
        #pragma unroll
        for (int u = 0; u < 4; u++) {
            int idx = tid + u * 256;            // 1024 float4 chunks
            int r = idx >> 4, fc = (idx & 15) * 4;
            float4 v = *reinterpret_cast<const float4*>(X + (row0 + r) * FIN + k0 + fc);
            union { unsigned short s[4]; uint2 u2; } ph, pl;
            ph.s[0] = f2bf(v.x); pl.s[0] = f2bf(v.x - bf2f(ph.s[0]));
            ph.s[1] = f2bf(v.y); pl.s[1] = f2bf(v.y - bf2f(ph.s[1]));
            ph.s[2] = f2bf(v.z); pl.s[2] = f2bf(v.z - bf2f(ph.s[2]));
            ph.s[3] = f2bf(v.w); pl.s[3] = f2bf(v.w - bf2f(ph.s[3]));
            *reinterpret_cast<uint2*>(&ah[r][fc]) = ph.u2;
            *reinterpret_cast<uint2*>(&al[r][fc]) = pl.u2;
        }
        // stage B panel: W[0..128][k0..+64] -> hi/lo bf16
        #pragma unroll
        for (int u = 0; u < 8; u++) {
            int idx = tid + u * 256;            // 2048 float4 chunks
            int hh = idx >> 4, fc = (idx & 15) * 4;
            float4 v = *reinterpret_cast<const float4*>(W + hh * FIN + k0 + fc);
            union { unsigned short s[4]; uint2 u2; } ph, pl;
            ph.s[0] = f2bf(v.x); pl.s[0] = f2bf(v.x - bf2f(ph.s[0]));
            ph.s[1] = f2bf(v.y); pl.s[1] = f2bf(v.y - bf2f(ph.s[1]));
            ph.s[2] = f2bf(v.z); pl.s[2] = f2bf(v.z - bf2f(ph.s[2]));
            ph.s[3] = f2bf(v.w); pl.s[3] = f2bf(v.w - bf2f(ph.s[3]));
            *reinterpret_cast<uint2*>(&bh[hh][fc]) = ph.u2;
            *reinterpret_cast<uint2*>(&bl[hh][fc]) = pl.u2;
        }
        __syncthreads();
        #pragma unroll
        for (int ks = 0; ks < 64; ks += 32) {
            short8 afh = *reinterpret_cast<const short8*>(&ah[w * 16 + lm][ks + q * 8]);
            short8 afl = *reinterpret_cast<const short8*>(&al[w * 16 + lm][ks + q * 8]);
            #pragma unroll
            for (int nt = 0; nt < 8; nt++) {
                short8 bfh = *reinterpret_cast<const short8*>(&bh[nt * 16 + lm][ks + q * 8]);
                short8 bfl = *reinterpret_cast<const short8*>(&bl[nt * 16 + lm][ks + q * 8]);
                acc[nt] = __builtin_amdgcn_mfma_f32_16x16x32_bf16(afh, bfh, acc[nt], 0, 0, 0);
                acc[nt] = __builtin_amdgcn_mfma_f32_16x16x32_bf16(afh, bfl, acc[nt], 0, 0, 0);
                acc[nt] = __builtin_amdgcn_mfma_f32_16x16x32_bf16(afl, bfh, acc[nt], 0, 0, 0);
            }
        }
        __syncthreads();
    }

    // epilogue: bias, src/dst dots, bf16 transpose via LDS
    // C/D layout: col(h within tile)=lm, row(m within tile)=q*4+r
    float s1[4] = {0.f, 0.f, 0.f, 0.f}, s2[4] = {0.f, 0.f, 0.f, 0.f};
    #pragma unroll
    for (int nt = 0; nt < 8; nt++) {
        #pragma unroll
        for (int r = 0; r < 4; r++) {
            float v = acc[nt][r] + bwv[nt];
            s1[r] += v * a1v[nt];
            s2[r] += v * a2v[nt];
            tb[nt * 16 + lm][w * 16 + q * 4 + r] = f2bf(v);
        }
    }
    #pragma unroll
    for (int r = 0; r < 4; r++) {
        #pragma unroll
        for (int o = 1; o < 16; o <<= 1) {
            s1[r] += __shfl_xor(s1[r], o);
            s2[r] += __shfl_xor(s2[r], o);
        }
    }
    if (lm == 0) {
        #pragma unroll
        for (int r = 0; r < 4; r++) {
            long row = row0 + w * 16 + q * 4 + r;
            src[row] = s1[r];
            dst[row] = s2[r];
        }
    }
    __syncthreads();
    const int b = (int)(row0 >> 11);
    const int n0 = (int)(row0 & 2047);
    #pragma unroll
    for (int u = 0; u < 4; u++) {
        int idx = tid + u * 256;               // 1024 uint4 chunks of [128][64]
        int hh = idx >> 3, c = idx & 7;
        *reinterpret_cast<uint4*>(whbT + ((size_t)(b * HDIM + hh)) * NDIM + n0 + c * 8) =
            *reinterpret_cast<const uint4*>(&tb[hh][c * 8]);
    }
}

// ---------------- Kernel 2: fused masked-softmax attention via MFMA ----------------
#define TI 64
#define TJ 64
#define LDP 72

__global__ __launch_bounds__(256) void k_attn(const int* __restrict__ adj,
                                              const unsigned short* __restrict__ whbT,
                                              const float* __restrict__ src,
                                              const float* __restrict__ dst,
                                              const float* __restrict__ ba_p,
                                              float* __restrict__ out) {
    __shared__ unsigned short whsT[HDIM][LDP];   // 18 KB  [h][j] bf16
    __shared__ unsigned short wt[TI][LDP];       // 9 KB   [i][j] bf16
    __shared__ float s_src[TI];
    __shared__ float lred[TI][4];
    __shared__ float linv_s[TI];

    const int tid = threadIdx.x;
    const int b = blockIdx.x >> 5;
    const int i0 = (blockIdx.x & 31) * TI;

    if (tid < TI) s_src[tid] = src[b * NDIM + i0 + tid] + ba_p[0];
    __syncthreads();

    const int wave = tid >> 6, lane = tid & 63;
    const int wtrow = tid >> 2, wtg = tid & 3;
    const long adjrow = ((long)(b * NDIM + i0 + wtrow)) * NDIM;
    const float* dstb = dst + b * NDIM;
    const unsigned short* whb = whbT + (size_t)b * HDIM * NDIM;

    floatx4 acc[2][4];
    #pragma unroll
    for (int mi = 0; mi < 2; mi++)
        #pragma unroll
        for (int hj = 0; hj < 4; hj++)
            acc[mi][hj] = (floatx4){0.f, 0.f, 0.f, 0.f};
    float lpart = 0.f;

    const int ib = (wave & 1) * 32;
    const int hb = (wave >> 1) * 64;
    const int lm = lane & 15, q = lane >> 4;

    for (int j0 = 0; j0 < NDIM; j0 += TJ) {
        #pragma unroll
        for (int u = 0; u < 4; u++) {
            int idx = tid + u * 256;
            int hh = idx >> 3, c = idx & 7;
            *reinterpret_cast<uint4*>(&whsT[hh][c * 8]) =
                *reinterpret_cast<const uint4*>(whb + (size_t)hh * NDIM + j0 + c * 8);
        }
        const float si = s_src[wtrow];
        #pragma unroll
        for (int qq = 0; qq < 4; qq++) {
            int jj = qq * 16 + wtg * 4;
            int4 av = *reinterpret_cast<const int4*>(adj + adjrow + j0 + jj);
            float4 dv = *reinterpret_cast<const float4*>(dstb + j0 + jj);
            float x0 = si + dv.x, x1 = si + dv.y, x2 = si + dv.z, x3 = si + dv.w;
            x0 = x0 > 0.f ? x0 : 0.01f * x0;
            x1 = x1 > 0.f ? x1 : 0.01f * x1;
            x2 = x2 > 0.f ? x2 : 0.01f * x2;
            x3 = x3 > 0.f ? x3 : 0.01f * x3;
            float w0 = av.x > 0 ? __expf(x0) : 0.f;
            float w1 = av.y > 0 ? __expf(x1) : 0.f;
            float w2 = av.z > 0 ? __expf(x2) : 0.f;
            float w3 = av.w > 0 ? __expf(x3) : 0.f;
            lpart += (w0 + w1) + (w2 + w3);
            union { unsigned short u[4]; uint2 v; } p;
            p.u[0] = f2bf(w0); p.u[1] = f2bf(w1); p.u[2] = f2bf(w2); p.u[3] = f2bf(w3);
            *reinterpret_cast<uint2*>(&wt[wtrow][jj]) = p.v;
        }
        __syncthreads();
        #pragma unroll
        for (int k0 = 0; k0 < TJ; k0 += 32) {
            short8 af[2], bfr[4];
            af[0] = *reinterpret_cast<const short8*>(&wt[ib + lm][k0 + q * 8]);
            af[1] = *reinterpret_cast<const short8*>(&wt[ib + 16 + lm][k0 + q * 8]);
            #pragma unroll
            for (int hj = 0; hj < 4; hj++)
                bfr[hj] = *reinterpret_cast<const short8*>(&whsT[hb + hj * 16 + lm][k0 + q * 8]);
            #pragma unroll
            for (int mi = 0; mi < 2; mi++)
                #pragma unroll
                for (int hj = 0; hj < 4; hj++)
                    acc[mi][hj] = __builtin_amdgcn_mfma_f32_16x16x32_bf16(
                        af[mi], bfr[hj], acc[mi][hj], 0, 0, 0);
        }
        __syncthreads();
    }

    lred[wtrow][wtg] = lpart;
    __syncthreads();
    if (tid < TI) {
        float l = lred[tid][0] + lred[tid][1] + lred[tid][2] + lred[tid][3];
        linv_s[tid] = l > 0.f ? 1.f / l : 0.f;
    }
    __syncthreads();

    #pragma unroll
    for (int mi = 0; mi < 2; mi++) {
        #pragma unroll
        for (int r = 0; r < 4; r++) {
            int il = ib + mi * 16 + q * 4 + r;
            float li = linv_s[il];
            long obase = ((long)(b * NDIM + i0 + il)) * HDIM + hb + lm;
            #pragma unroll
            for (int hj = 0; hj < 4; hj++) {
                float x = acc[mi][hj][r] * li;
                x = x > 0.f ? x : (__expf(x) - 1.f);
                out[obase + hj * 16] = x;
            }
        }
    }
}

extern "C" void kernel_launch(void* const* d_in, const int* in_sizes, int n_in,
                              void* d_out, int out_size, void* d_ws, size_t ws_size,
                              hipStream_t stream) {
    const float* X  = (const float*)d_in[0];   // [16,2048,256]
    const int* adj  = (const int*)d_in[1];     // [16,2048,2048]
    const float* W  = (const float*)d_in[2];   // [128,256]
    const float* bW = (const float*)d_in[3];   // [128]
    const float* a  = (const float*)d_in[4];   // [1,256]
    const float* ba = (const float*)d_in[5];   // [1]
    float* out = (float*)d_out;                // [16,2048,128]

    float* srcv = (float*)d_ws;                        // B*N
    float* dstv = srcv + BDIM * NDIM;                  // B*N
    unsigned short* whbT = (unsigned short*)(dstv + BDIM * NDIM);  // B*H*N bf16 (8 MB)

    k_wh<<<BDIM * NDIM / 64, 256, 0, stream>>>(X, W, bW, a, srcv, dstv, whbT);
    k_attn<<<BDIM * (NDIM / TI), 256, 0, stream>>>(adj, whbT, srcv, dstv, ba, out);
}